// Round 7
// baseline (149.346 us; speedup 1.0000x reference)
//
#include <hip/hip_runtime.h>
#include <math.h>

#define A_ 5
#define C_ 20
#define N_ 64
#define H_ 52
#define W_ 52
#define HW_ (H_ * W_)        // 2704
#define M_ 32
#define CH_ (A_ * (5 + C_))  // 125
#define CPBLK 128            // cells per block (256 thr = 128 pairs)
#define NBX ((HW_ + CPBLK - 1) / CPBLK)   // 22
#define NBLK (NBX * N_)                   // 1408

// TWO lanes per cell: even lane owns anchors {0,1,2}, odd lane {3,4}.
// Doubles resident waves vs R6 (5632 waves, ~5.5/SIMD) and halves the
// per-wave compute span -> ~2x time-averaged bytes in flight (the measured
// limiter: main ran at ~2x its 13.7us HBM floor). Pair merge via shfl_xor(1).
__global__ __launch_bounds__(256) void yolo_main(
    const float* __restrict__ x,       // (N, 125, H, W)
    const float* __restrict__ anchors, // (5, 2)
    const float* __restrict__ gt,      // (N, 32, 4)
    const int* __restrict__ glab,      // (N, 32)
    const void* img_h_p, const void* img_w_p,
    float* __restrict__ ws)            // SoA: (3, NBLK)
{
    const int tid  = threadIdx.x;
    const int sub  = tid & 1;           // 0: anchors 0..2, 1: anchors 3..4
    const int p    = tid >> 1;          // pair (cell slot) 0..127
    const int n    = blockIdx.y;
    const int cell = blockIdx.x * CPBLK + p;
    const bool valid = cell < HW_;

    int ibw = *(const int*)img_w_p;
    float img_w = (ibw > 0 && ibw < 1000000) ? (float)ibw : *(const float*)img_w_p;
    int ibh = *(const int*)img_h_p;
    float img_h = (ibh > 0 && ibh < 1000000) ? (float)ibh : *(const float*)img_h_p;
    const float sx = img_w / (float)W_;
    const float sy = img_h / (float)H_;

    float obj = 0.f, bbx = 0.f, clf = 0.f;

    if (valid) {
        const int a0 = sub ? 3 : 0;     // first owned anchor
        const size_t base = (size_t)n * CH_ * HW_ + cell;

        // ---- bulk-issue owned box-channel loads (2 x 128B segs / instr) ----
        float t[3][5];
        #pragma unroll
        for (int i = 0; i < 2; ++i)
            #pragma unroll
            for (int v = 0; v < 5; ++v)
                t[i][v] = x[base + (size_t)((a0 + i) * 25 + v) * HW_];
        #pragma unroll
        for (int v = 0; v < 5; ++v)     // third anchor: even lanes only
            t[2][v] = (sub == 0) ? x[base + (size_t)(2 * 25 + v) * HW_] : 0.f;

        const int wi = cell % W_;
        const int hi = cell / W_;

        // ---- owned boxes in registers ----
        float X1[3], Y1[3], X2[3], Y2[3], AP[3], OVv[3];
        #pragma unroll
        for (int i = 0; i < 3; ++i) {
            int ai = a0 + i;
            ai = (ai > 4) ? 4 : ai;     // clamp for odd-lane dummy slot
            float ax = anchors[2 * ai];
            float ay = anchors[2 * ai + 1];
            float bx = 1.f / (1.f + __expf(-t[i][0])) + (float)wi * sx;
            float by = 1.f / (1.f + __expf(-t[i][1])) + (float)hi * sy;
            float bw = sx * ax * __expf(t[i][2]);
            float bh = sy * ay * __expf(t[i][3]);
            X1[i] = bx; Y1[i] = by; X2[i] = bx + bw; Y2[i] = by + bh;
            AP[i] = (X2[i] - X1[i]) * (Y2[i] - Y1[i]);   // match reference
            OVv[i] = 1.f / (1.f + __expf(-t[i][4]));
        }
        if (sub) {                      // neutralize dummy slot 2
            X1[2] = Y1[2] = X2[2] = Y2[2] = 0.f;
            AP[2] = 0.f;
            OVv[2] = -1e30f;            // never the bomax
        }

        // ---- single m-loop, 3 (or 2) independent argmax chains ----
        float BIv[3] = {0.f, 0.f, 0.f};
        float BUv[3] = {1.f, 1.f, 1.f};
        int   BMv[3] = {0, 0, 0};
        const float4* gtv = (const float4*)(gt + (size_t)n * M_ * 4);
        #pragma unroll 8
        for (int m = 0; m < M_; ++m) {
            float4 g = gtv[m];          // wave-uniform -> scalar path
            float area = (g.z - g.x) * (g.w - g.y);
            #pragma unroll
            for (int i = 0; i < 3; ++i) {
                float wq = fminf(X2[i], g.z) - fmaxf(X1[i], g.x);
                float hq = fminf(Y2[i], g.w) - fmaxf(Y1[i], g.y);
                wq = fmaxf(wq, 0.f);
                hq = fmaxf(hq, 0.f);
                float inter = wq * hq;  // dummy slot: always 0 -> never wins
                float uni = AP[i] + area - inter;
                if (inter * BUv[i] > BIv[i] * uni) {
                    BIv[i] = inter; BUv[i] = uni; BMv[i] = m;
                }
            }
        }

        // ---- local select among owned anchors (first-max in anchor order) --
        float Li = BIv[0], Lu = BUv[0], Lo = OVv[0];
        float lx1 = X1[0], ly1 = Y1[0], lx2 = X2[0], ly2 = Y2[0];
        int   La = a0, Lm = BMv[0];
        float lbomax = OVv[0];
        #pragma unroll
        for (int i = 1; i < 3; ++i) {
            lbomax = fmaxf(lbomax, OVv[i]);
            if (BIv[i] * Lu > Li * BUv[i]) {
                Li = BIv[i]; Lu = BUv[i]; Lo = OVv[i];
                lx1 = X1[i]; ly1 = Y1[i]; lx2 = X2[i]; ly2 = Y2[i];
                La = a0 + i; Lm = BMv[i];
            }
        }

        // ---- pair merge (partner = lane^1). Lower anchors win ties. ----
        float pi_ = __shfl_xor(Li, 1, 64);
        float pu_ = __shfl_xor(Lu, 1, 64);
        float po_ = __shfl_xor(Lo, 1, 64);
        float px1 = __shfl_xor(lx1, 1, 64);
        float py1 = __shfl_xor(ly1, 1, 64);
        float px2 = __shfl_xor(lx2, 1, 64);
        float py2 = __shfl_xor(ly2, 1, 64);
        int   pa_ = __shfl_xor(La, 1, 64);
        int   pm_ = __shfl_xor(Lm, 1, 64);
        float pbm = __shfl_xor(lbomax, 1, 64);

        // own wins: sub==0 keeps own unless partner strictly beats;
        // sub==1 keeps own only if own strictly beats partner.
        bool ownWins = sub ? (Li * pu_ > pi_ * Lu)
                           : !(pi_ * Lu > Li * pu_);
        float Bi = ownWins ? Li  : pi_;
        float Bu = ownWins ? Lu  : pu_;
        float O  = ownWins ? Lo  : po_;
        float wx1 = ownWins ? lx1 : px1;
        float wy1 = ownWins ? ly1 : py1;
        float wx2 = ownWins ? lx2 : px2;
        float wy2 = ownWins ? ly2 : py2;
        int   Ba = ownWins ? La : pa_;
        int   Bm = ownWins ? Lm : pm_;
        float bomax = fmaxf(lbomax, pbm);

        if (Bi > 0.f) {
            // ---- CE split across the pair: 10 scores each ----
            const size_t sb = base + (size_t)(Ba * 25 + 5) * HW_;
            const int lab = glab[n * M_ + Bm];
            float sc[10];
            #pragma unroll
            for (int jj = 0; jj < 10; ++jj)
                sc[jj] = x[sb + (size_t)(2 * jj + sub) * HW_];
            float mx = sc[0];
            #pragma unroll
            for (int jj = 1; jj < 10; ++jj) mx = fmaxf(mx, sc[jj]);
            mx = fmaxf(mx, __shfl_xor(mx, 1, 64));      // pair max (exact)
            float se = 0.f;
            #pragma unroll
            for (int jj = 0; jj < 10; ++jj) se += __expf(sc[jj] - mx);
            se += __shfl_xor(se, 1, 64);                // pair sum
            float scl = -INFINITY;
            #pragma unroll
            for (int jj = 0; jj < 10; ++jj)
                scl = (2 * jj + sub == lab) ? sc[jj] : scl;
            scl = fmaxf(scl, __shfl_xor(scl, 1, 64));   // exactly one lane has it

            if (sub == 0) {             // one lane emits the cell's losses
                float d = O - Bi / Bu;
                obj = d * d;
                float4 g = ((const float4*)gt)[n * M_ + Bm];
                float d0 = wx1 - g.x;
                float d1 = wy1 - g.y;
                float d2 = sqrtf(wx2) - sqrtf(g.z);
                float d3 = sqrtf(wy2) - sqrtf(g.w);
                bbx = d0 * d0 + d1 * d1 + d2 * d2 + d3 * d3;
                clf = mx + __logf(se) - scl;
            }
        } else {
            if (sub == 0) obj = 0.5f * bomax * bomax;
        }
    }

    // ---- wave reduce + block reduce (4 waves) ----
    #pragma unroll
    for (int off = 32; off > 0; off >>= 1) {
        obj += __shfl_down(obj, off, 64);
        bbx += __shfl_down(bbx, off, 64);
        clf += __shfl_down(clf, off, 64);
    }
    __shared__ float s_red[4][3];
    if ((tid & 63) == 0) {
        const int wid = tid >> 6;
        s_red[wid][0] = obj; s_red[wid][1] = bbx; s_red[wid][2] = clf;
    }
    __syncthreads();
    if (tid == 0) {
        float oo = 0.f, bs = 0.f, cc = 0.f;
        #pragma unroll
        for (int w = 0; w < 4; ++w) {
            oo += s_red[w][0]; bs += s_red[w][1]; cc += s_red[w][2];
        }
        const int bid = blockIdx.y * gridDim.x + blockIdx.x;
        ws[0 * NBLK + bid] = oo;
        ws[1 * NBLK + bid] = bs;
        ws[2 * NBLK + bid] = cc;
    }
}

__global__ __launch_bounds__(1024) void yolo_reduce(
    const float* __restrict__ ws, float* __restrict__ out)
{
    __shared__ float s_red[16][3];
    const int tid = threadIdx.x;
    float o = 0.f, b = 0.f, c = 0.f;
    for (int e = tid; e < NBLK; e += 1024) {   // 2 coalesced iterations
        o += ws[0 * NBLK + e];
        b += ws[1 * NBLK + e];
        c += ws[2 * NBLK + e];
    }
    #pragma unroll
    for (int off = 32; off > 0; off >>= 1) {
        o += __shfl_down(o, off, 64);
        b += __shfl_down(b, off, 64);
        c += __shfl_down(c, off, 64);
    }
    const int wid = tid >> 6;
    if ((tid & 63) == 0) {
        s_red[wid][0] = o; s_red[wid][1] = b; s_red[wid][2] = c;
    }
    __syncthreads();
    if (tid == 0) {
        float oo = 0.f, bb = 0.f, cc = 0.f;
        #pragma unroll
        for (int w = 0; w < 16; ++w) {
            oo += s_red[w][0]; bb += s_red[w][1]; cc += s_red[w][2];
        }
        out[0] = oo; out[1] = bb; out[2] = cc;
    }
}

extern "C" void kernel_launch(void* const* d_in, const int* in_sizes, int n_in,
                              void* d_out, int out_size, void* d_ws, size_t ws_size,
                              hipStream_t stream) {
    (void)in_sizes; (void)n_in; (void)out_size; (void)ws_size;
    const float* x    = (const float*)d_in[0];
    const float* anch = (const float*)d_in[1];
    const float* gt   = (const float*)d_in[2];
    const int*   gl   = (const int*)d_in[3];
    const void*  ih   = d_in[4];
    const void*  iw   = d_in[5];
    float* out = (float*)d_out;
    float* ws  = (float*)d_ws;

    dim3 grid(NBX, N_);
    yolo_main<<<grid, dim3(256), 0, stream>>>(x, anch, gt, gl, ih, iw, ws);
    yolo_reduce<<<1, 1024, 0, stream>>>(ws, out);
}